// Round 17
// baseline (108.901 us; speedup 1.0000x reference)
//
#include <hip/hip_runtime.h>
#include <math.h>

#define N_TOK 2048
#define D_MODEL 512
#define NHEAD 8
#define DK 64
#define LOG2E 1.44269504f
#define QSCALE 0.18033688f   // 0.125 * log2(e)
#define KTILE 6144           // shorts per 64-key K tile (4096 main + 2048 aug)
#define KHEAD (32 * KTILE)   // shorts per head in Kf
#define KSPLIT 8             // one partial per (z,wave)

typedef __attribute__((ext_vector_type(8))) short short8;
typedef __attribute__((ext_vector_type(4))) short short4v;
typedef __attribute__((ext_vector_type(4))) float f32x4;
typedef __attribute__((ext_vector_type(16))) float f32x16;
typedef __attribute__((ext_vector_type(4))) unsigned int u32x4;

__device__ __forceinline__ short f2bf(float x) {
    unsigned u = __float_as_uint(x);
    u = (u + 0x7fffu + ((u >> 16) & 1u)) >> 16;   // round-to-nearest-even
    return (short)u;
}

__device__ __forceinline__ float bf2f(short s) {
    return __uint_as_float(((unsigned)(unsigned short)s) << 16);
}

__device__ __forceinline__ void split2(float x, short& h_, short& l_) {
    h_ = f2bf(x);
    l_ = f2bf(x - bf2f(h_));
}

__device__ __forceinline__ void split3(float x, short& h_, short& m_, short& l_) {
    h_ = f2bf(x);
    float r = x - bf2f(h_);
    m_ = f2bf(r);
    l_ = f2bf(r - bf2f(m_));
}

__device__ __forceinline__ unsigned cvt_pk_bf16(float lo, float hi) {
    unsigned r;
    asm("v_cvt_pk_bf16_f32 %0, %1, %2" : "=v"(r) : "v"(lo), "v"(hi));
    return r;
}

__device__ __forceinline__ float head_c(int h) {
    // c_h = -log2e / (2*spread^2), spread = 1 + 5*(20^(h/7)-1)/19
    float tt = (float)h * (1.0f / 7.0f);
    float sp = 1.0f + 5.0f * (__builtin_exp2f(tt * 4.3219281f) - 1.0f) * (1.0f / 19.0f);
    return -LOG2E / (2.0f * sp * sp);
}

// ---------------- Prep (small): weights->bf16, K-aug RBF frags, mask -------
// bid <256: weight prep. 256..263: aug+mask tables (32x32 A-fragment order).
__global__ __launch_bounds__(256) void prep_all_kernel(
    const float* __restrict__ coords, const unsigned char* __restrict__ mask,
    const float* __restrict__ qp, const float* __restrict__ kp,
    const float* __restrict__ vp, const float* __restrict__ ow,
    short* __restrict__ Wt, short* __restrict__ Wo,
    short* __restrict__ Kf, float* __restrict__ mpen,
    unsigned* __restrict__ tflag)
{
    __shared__ float tile[64][65];
    const int bid = blockIdx.x;
    const int t = threadIdx.x;

    if (bid < 256) {
        int i = bid;
        int z = i >> 6;
        int bx = i & 7, by = (i >> 3) & 7;
        if (z == 3) {
            int m0 = bx * 64, j0 = by * 64, hh = by;
            for (int ii = t; ii < 4096; ii += 256) {
                int r = ii >> 6, kk = ii & 63;
                Wo[(size_t)(m0 + r) * 512 + j0 + kk] =
                    f2bf(ow[(size_t)(m0 + r) * 512 + kk * 8 + hh]);
            }
            return;
        }
        const float* src = z == 0 ? qp : (z == 1 ? kp : vp);
        const int h = bx, d0 = by * 64;
        for (int ii = t; ii < 4096; ii += 256) {
            int r = ii >> 6, c = ii & 63;
            tile[r][c] = src[((size_t)h * 512 + d0 + r) * 64 + c];
        }
        __syncthreads();
        short* W = Wt + (size_t)z * 512 * 512;
        for (int ii = t; ii < 4096; ii += 256) {
            int cr = ii >> 6, dc_ = ii & 63;
            W[(size_t)(h * 64 + cr) * 512 + d0 + dc_] = f2bf(tile[dc_][cr]);
        }
    } else {
        // ---- K-aug RBF fragments (32x32 A order) + mask tables ----
        int j = (bid - 256) * 256 + t;
        float x = coords[j * 3 + 0], y = coords[j * 3 + 1], z = coords[j * 3 + 2];
        unsigned char mk = mask[j];
        mpen[j] = mk ? -1e9f : 0.f;
        unsigned long long b = __ballot(mk != 0);
        if ((t & 63) == 0) tflag[j >> 6] = (b != 0ull) ? 1u : 0u;
        float n2 = x * x + y * y + z * z;
        const short one = (short)0x3F80;
        const int s = (j & 63) >> 5;
        const int m = j & 31;
        #pragma unroll
        for (int h = 0; h < NHEAD; ++h) {
            float c = head_c(h);
            short ahx, alx, ahy, aly, ahz, alz, k2a, k2b, k2c;
            split2(-2.f * c * x, ahx, alx);
            split2(-2.f * c * y, ahy, aly);
            split2(-2.f * c * z, ahz, alz);
            split3(c * n2, k2a, k2b, k2c);
            short8 g0, g1, g2, g3;
            g0[0] = ahx; g0[1] = alx; g0[2] = ahx; g0[3] = ahy;
            g0[4] = aly; g0[5] = ahy; g0[6] = ahz; g0[7] = alz;
            g1[0] = ahz; g1[1] = alx; g1[2] = aly; g1[3] = alz;
            g1[4] = k2a; g1[5] = k2b; g1[6] = k2c; g1[7] = one;
            g2[0] = one; g2[1] = one;
            #pragma unroll
            for (int e = 2; e < 8; ++e) g2[e] = 0;
            #pragma unroll
            for (int e = 0; e < 8; ++e) g3[e] = 0;
            short* base = Kf + (size_t)h * KHEAD + (size_t)(j >> 6) * KTILE
                        + 4096 + (size_t)s * 1024;
            *(short8*)(base + (size_t)m * 8) = g0;
            *(short8*)(base + (size_t)(m + 32) * 8) = g1;
            *(short8*)(base + 512 + (size_t)m * 8) = g2;
            *(short8*)(base + 512 + (size_t)(m + 32) * 8) = g3;
        }
    }
}

// ---------------- Stage 1: projection + LayerNorm via bf16 MFMA ------------
// grid (N/128, H, 3): 128-row tiles; f32 x converted to bf16 during staging.
// Epilogues emit 32x32 MFMA fragment orders (Q as B-op, K/V^T as A-op).
__global__ __launch_bounds__(256) void proj_ln_mfma_kernel(
    const float* __restrict__ xq, const float* __restrict__ xk,
    const float* __restrict__ xv, const short* __restrict__ Wt,
    const float* __restrict__ qlw, const float* __restrict__ qlb,
    const float* __restrict__ klw, const float* __restrict__ klb,
    const float* __restrict__ vlw, const float* __restrict__ vlb,
    short* __restrict__ Qf, short* __restrict__ Kf, short* __restrict__ Vf)
{
    __shared__ short Xs[128 * 64];   // 16 KB
    __shared__ short Ws[64 * 64];    // 8 KB
    const int z = blockIdx.z, h = blockIdx.y;
    const int n0 = blockIdx.x * 128;
    const int tid = threadIdx.x, w = tid >> 6, l = tid & 63;
    const int l15 = l & 15, lg = l >> 4;

    const float* X = z == 0 ? xq : (z == 1 ? xk : xv);
    const short* Wz = Wt + ((size_t)z * 512 + h * 64) * 512;

    const f32x4 zero4 = {0.f, 0.f, 0.f, 0.f};
    f32x4 acc[2][4];
    #pragma unroll
    for (int H = 0; H < 2; ++H)
        #pragma unroll
        for (int dc = 0; dc < 4; ++dc) acc[H][dc] = zero4;

    for (int kb = 0; kb < 8; ++kb) {
        const int d0 = kb * 64;
        __syncthreads();
        #pragma unroll
        for (int i = 0; i < 8; ++i) {
            int idx = tid + i * 256;
            int r = idx >> 4;
            int f = idx & 15;
            float4 xv4 = *(const float4*)(X + (size_t)(n0 + r) * 512 + d0 + f * 4);
            short4v pk;
            pk[0] = f2bf(xv4.x); pk[1] = f2bf(xv4.y);
            pk[2] = f2bf(xv4.z); pk[3] = f2bf(xv4.w);
            *(short4v*)(Xs + r * 64 + (((f >> 1) * 8) ^ ((r & 7) << 3)) + (f & 1) * 4) = pk;
        }
        #pragma unroll
        for (int i = 0; i < 2; ++i) {
            int c = tid + i * 256;
            int r = c >> 3, g = c & 7;
            short8 wv = *(const short8*)(Wz + (size_t)r * 512 + d0 + g * 8);
            *(short8*)(Ws + r * 64 + ((g * 8) ^ ((r & 7) << 3))) = wv;
        }
        __syncthreads();
        const int arowA = w * 16 + l15;
        const int arowB = 64 + arowA;
        const int asw = (arowA & 7) << 3;
        short8 aA0 = *(const short8*)(Xs + arowA * 64 + ((lg * 8) ^ asw));
        short8 aA1 = *(const short8*)(Xs + arowA * 64 + ((32 + lg * 8) ^ asw));
        short8 aB0 = *(const short8*)(Xs + arowB * 64 + ((lg * 8) ^ asw));
        short8 aB1 = *(const short8*)(Xs + arowB * 64 + ((32 + lg * 8) ^ asw));
        #pragma unroll
        for (int dc = 0; dc < 4; ++dc) {
            const int brow = dc * 16 + l15;
            short8 b0 = *(const short8*)(Ws + brow * 64 + ((lg * 8) ^ ((brow & 7) << 3)));
            short8 b1 = *(const short8*)(Ws + brow * 64 + ((32 + lg * 8) ^ ((brow & 7) << 3)));
            acc[0][dc] = __builtin_amdgcn_mfma_f32_16x16x32_bf16(aA0, b0, acc[0][dc], 0, 0, 0);
            acc[0][dc] = __builtin_amdgcn_mfma_f32_16x16x32_bf16(aA1, b1, acc[0][dc], 0, 0, 0);
            acc[1][dc] = __builtin_amdgcn_mfma_f32_16x16x32_bf16(aB0, b0, acc[1][dc], 0, 0, 0);
            acc[1][dc] = __builtin_amdgcn_mfma_f32_16x16x32_bf16(aB1, b1, acc[1][dc], 0, 0, 0);
        }
    }

    const float* lw  = z == 0 ? qlw : (z == 1 ? klw : vlw);
    const float* lbp = z == 0 ? qlb : (z == 1 ? klb : vlb);
    float wv_[4], bv_[4];
    #pragma unroll
    for (int dc = 0; dc < 4; ++dc) {
        wv_[dc] = lw[dc * 16 + l15];
        bv_[dc] = lbp[dc * 16 + l15];
    }

    #pragma unroll
    for (int H = 0; H < 2; ++H) {
        const int nb = n0 + H * 64;
        const int kt = nb >> 6;
        float mu[4], rs[4];
        #pragma unroll
        for (int reg = 0; reg < 4; ++reg) {
            float s = acc[H][0][reg] + acc[H][1][reg] + acc[H][2][reg] + acc[H][3][reg];
            #pragma unroll
            for (int off = 1; off < 16; off <<= 1) s += __shfl_xor(s, off);
            float m = s * (1.0f / 64.0f);
            float ss = 0.f;
            #pragma unroll
            for (int dc = 0; dc < 4; ++dc) { float d = acc[H][dc][reg] - m; ss += d * d; }
            #pragma unroll
            for (int off = 1; off < 16; off <<= 1) ss += __shfl_xor(ss, off);
            mu[reg] = m;
            rs[reg] = rsqrtf(ss * (1.0f / 64.0f) + 1e-5f);
        }
        if (z == 0) {
            short* Qh = Qf + (size_t)h * (N_TOK * DK);
            #pragma unroll
            for (int dc = 0; dc < 4; ++dc)
                #pragma unroll
                for (int reg = 0; reg < 4; ++reg) {
                    int n = nb + w * 16 + lg * 4 + reg;
                    float val = ((acc[H][dc][reg] - mu[reg]) * rs[reg] * wv_[dc] + bv_[dc]) * QSCALE;
                    size_t addr = (size_t)(n >> 5) * 2048 + dc * 512
                                + ((n & 31) + 32 * (l15 >> 3)) * 8 + (l15 & 7);
                    Qh[addr] = f2bf(val);
                }
        } else if (z == 1) {
            short* Kh = Kf + (size_t)h * KHEAD;
            const int sA = w >> 1;
            const int mA = (w & 1) * 16 + lg * 4;
            #pragma unroll
            for (int dc = 0; dc < 4; ++dc)
                #pragma unroll
                for (int reg = 0; reg < 4; ++reg) {
                    float val = (acc[H][dc][reg] - mu[reg]) * rs[reg] * wv_[dc] + bv_[dc];
                    size_t addr = (size_t)kt * KTILE + sA * 2048 + dc * 512
                                + (mA + reg + 32 * (l15 >> 3)) * 8 + (l15 & 7);
                    Kh[addr] = f2bf(val);
                }
        } else {
            short* Vh = Vf + (size_t)h * (N_TOK * DK);
            const int kc = w;
            const int g = lg >> 1;
            const int e0 = (lg & 1) * 4;
            #pragma unroll
            for (int dc = 0; dc < 4; ++dc) {
                int dt = dc >> 1;
                int m = (dc & 1) * 16 + l15;
                short4v p;
                #pragma unroll
                for (int reg = 0; reg < 4; ++reg)
                    p[reg] = f2bf((acc[H][dc][reg] - mu[reg]) * rs[reg] * wv_[dc] + bv_[dc]);
                size_t addr = (size_t)kt * 4096 + dt * 2048 + kc * 512
                            + (m + 32 * g) * 8 + e0;
                *(short4v*)(Vh + addr) = p;
            }
        }
    }
}

// ---------------- Stage 2: split-K flash attention (32x32 bf16 MFMA) -------
// grid 1024, head<->XCD affinity (h=bid&7). ZERO LDS, ZERO BARRIERS: each
// wave is an independent task (32 q-rows x 256 keys) writing its own partial
// (part = z*4+w, KSPLIT=8). Swapped QK via mfma_32x32x16; P redistribution
// fully in-register (cvt_pk + shfl_xor(32)); m=0 softmax; lane-local l.
__global__ __launch_bounds__(256) void attn_kernel(
    const short* __restrict__ Qf, const short* __restrict__ Kf,
    const short* __restrict__ Vf, const float* __restrict__ coords,
    const float* __restrict__ mpen, const unsigned* __restrict__ tflag,
    short* __restrict__ PO, float* __restrict__ PL)
{
    const int tid = threadIdx.x;
    const int w = tid >> 6, l = tid & 63;
    const int q31 = l & 31;
    const bool hi = (l >= 32);
    const int rbase = hi ? 4 : 0;
    const int bid = blockIdx.x;
    const int h  = bid & 7;              // head == XCD
    const int qt = (bid >> 3) & 63;      // 32-q tile
    const int z  = bid >> 9;             // key half 0/1
    const int n0 = qt * 32;
    const int part = z * 4 + w;          // partial slot 0..7

    // Q B-fragments (4 d-chunks of 16)
    const short* qbase = Qf + (size_t)h * (N_TOK * DK) + (size_t)qt * 2048 + l * 8;
    short8 qf[4];
    #pragma unroll
    for (int c = 0; c < 4; ++c) qf[c] = *(const short8*)(qbase + c * 512);

    // Q-side augmented RBF B-fragments
    const float ch = head_c(h);
    const int qn = n0 + q31;
    const float qx = coords[qn * 3 + 0];
    const float qy = coords[qn * 3 + 1];
    const float qz = coords[qn * 3 + 2];
    const float cq2 = ch * (qx * qx + qy * qy + qz * qz);
    short8 qaug0, qaug1;
    {
        const short one = (short)0x3F80;
        short qhx, qlx, qhy, qly, qhz, qlz, q2a, q2b, q2c;
        split2(qx, qhx, qlx);
        split2(qy, qhy, qly);
        split2(qz, qhz, qlz);
        split3(cq2, q2a, q2b, q2c);
        if (!hi) {
            qaug0[0] = qhx; qaug0[1] = qhx; qaug0[2] = qlx; qaug0[3] = qhy;
            qaug0[4] = qhy; qaug0[5] = qly; qaug0[6] = qhz; qaug0[7] = qhz;
            qaug1[0] = q2b; qaug1[1] = q2c;
            #pragma unroll
            for (int e = 2; e < 8; ++e) qaug1[e] = 0;
        } else {
            qaug0[0] = qlz; qaug0[1] = qlx; qaug0[2] = qly; qaug0[3] = qlz;
            qaug0[4] = one; qaug0[5] = one; qaug0[6] = one; qaug0[7] = q2a;
            #pragma unroll
            for (int e = 0; e < 8; ++e) qaug1[e] = 0;
        }
    }

    const f32x16 zero16 = {0,0,0,0, 0,0,0,0, 0,0,0,0, 0,0,0,0};
    f32x16 oacc0 = zero16, oacc1 = zero16;
    float l_ = 0.f;

    const short* Kfh = Kf + (size_t)h * KHEAD;
    const short* Vfh = Vf + (size_t)h * (N_TOK * DK);

    for (int t = 0; t < 4; ++t) {
        const int kt = z * 16 + w * 4 + t;   // 64-key tile
        const int kbase = kt * 64;
        #pragma unroll
        for (int s = 0; s < 2; ++s) {
            const short* kp = Kfh + (size_t)kt * KTILE + s * 2048 + l * 8;
            const short* ap = Kfh + (size_t)kt * KTILE + 4096 + s * 1024 + l * 8;
            const short* vp = Vfh + (size_t)kt * 4096 + s * 1024 + l * 8;

            // ---- QK^T (swapped) + RBF-arg MFMA ----
            f32x16 sacc = zero16, aacc = zero16;
            #pragma unroll
            for (int c = 0; c < 4; ++c) {
                short8 kfr = *(const short8*)(kp + c * 512);
                sacc = __builtin_amdgcn_mfma_f32_32x32x16_bf16(kfr, qf[c], sacc, 0, 0, 0);
            }
            {
                short8 a0 = *(const short8*)(ap);
                short8 a1 = *(const short8*)(ap + 512);
                aacc = __builtin_amdgcn_mfma_f32_32x32x16_bf16(a0, qaug0, aacc, 0, 0, 0);
                aacc = __builtin_amdgcn_mfma_f32_32x32x16_bf16(a1, qaug1, aacc, 0, 0, 0);
            }

            // ---- RBF modulation ----
            #pragma unroll
            for (int r = 0; r < 16; ++r) {
                float rb = __builtin_exp2f(aacc[r]);
                rb = fminf(fmaxf(rb, 0.1f), 0.9f);
                sacc[r] *= rb;
            }
            if (tflag[kt]) {
                #pragma unroll
                for (int r = 0; r < 16; ++r)
                    sacc[r] += mpen[kbase + s * 32 + ((r & 3) + 8 * (r >> 2) + rbase)];
            }

            // ---- P = exp2(s) (m=0), lane-local l partial ----
            #pragma unroll
            for (int r = 0; r < 16; ++r) sacc[r] = __builtin_exp2f(sacc[r]);
            {
                float s01 = (sacc[0] + sacc[1]) + (sacc[2] + sacc[3]);
                float s23 = (sacc[4] + sacc[5]) + (sacc[6] + sacc[7]);
                float s45 = (sacc[8] + sacc[9]) + (sacc[10] + sacc[11]);
                float s67 = (sacc[12] + sacc[13]) + (sacc[14] + sacc[15]);
                l_ += (s01 + s23) + (s45 + s67);
            }

            // ---- pack + in-register redistribution (shfl across halves) ----
            unsigned U0 = cvt_pk_bf16(sacc[0], sacc[1]);
            unsigned U1 = cvt_pk_bf16(sacc[2], sacc[3]);
            unsigned U2 = cvt_pk_bf16(sacc[4], sacc[5]);
            unsigned U3 = cvt_pk_bf16(sacc[6], sacc[7]);
            unsigned U4 = cvt_pk_bf16(sacc[8], sacc[9]);
            unsigned U5 = cvt_pk_bf16(sacc[10], sacc[11]);
            unsigned U6 = cvt_pk_bf16(sacc[12], sacc[13]);
            unsigned U7 = cvt_pk_bf16(sacc[14], sacc[15]);
            unsigned W0 = (unsigned)__shfl_xor((int)U0, 32);
            unsigned W1 = (unsigned)__shfl_xor((int)U1, 32);
            unsigned W2 = (unsigned)__shfl_xor((int)U2, 32);
            unsigned W3 = (unsigned)__shfl_xor((int)U3, 32);
            unsigned W4 = (unsigned)__shfl_xor((int)U4, 32);
            unsigned W5 = (unsigned)__shfl_xor((int)U5, 32);
            unsigned W6 = (unsigned)__shfl_xor((int)U6, 32);
            unsigned W7 = (unsigned)__shfl_xor((int)U7, 32);

            u32x4 b0v, b1v;
            b0v[0] = hi ? W2 : U0;  b0v[1] = hi ? W3 : U1;
            b0v[2] = hi ? U2 : W0;  b0v[3] = hi ? U3 : W1;
            b1v[0] = hi ? W6 : U4;  b1v[1] = hi ? W7 : U5;
            b1v[2] = hi ? U6 : W4;  b1v[3] = hi ? U7 : W5;
            short8 pb0 = __builtin_bit_cast(short8, b0v);
            short8 pb1 = __builtin_bit_cast(short8, b1v);

            // ---- PV (swapped): O^T += V^T * P^T ----
            {
                short8 v00 = *(const short8*)(vp);
                short8 v01 = *(const short8*)(vp + 512);
                short8 v10 = *(const short8*)(vp + 2048);
                short8 v11 = *(const short8*)(vp + 2048 + 512);
                oacc0 = __builtin_amdgcn_mfma_f32_32x32x16_bf16(v00, pb0, oacc0, 0, 0, 0);
                oacc0 = __builtin_amdgcn_mfma_f32_32x32x16_bf16(v01, pb1, oacc0, 0, 0, 0);
                oacc1 = __builtin_amdgcn_mfma_f32_32x32x16_bf16(v10, pb0, oacc1, 0, 0, 0);
                oacc1 = __builtin_amdgcn_mfma_f32_32x32x16_bf16(v11, pb1, oacc1, 0, 0, 0);
            }
        }
    }

    // finalize lane-local l (both halves of the same q)
    l_ += __shfl_xor(l_, 32);

    // ---- direct partial write (no LDS, no barrier) ----
    size_t p = ((size_t)part * NHEAD + h) * N_TOK + n0 + q31;
    if (!hi) PL[p] = l_;
    #pragma unroll
    for (int g2 = 0; g2 < 4; ++g2) {
        short4v o0, o1;
        #pragma unroll
        for (int e = 0; e < 4; ++e) {
            o0[e] = f2bf(oacc0[g2 * 4 + e]);
            o1[e] = f2bf(oacc1[g2 * 4 + e]);
        }
        *(short4v*)(PO + p * 64 + 8 * g2 + rbase) = o0;
        *(short4v*)(PO + p * 64 + 32 + 8 * g2 + rbase) = o1;
    }
}

// ---------------- Stage 3: merge 8 partials + output projection (fused) ----
// grid (N/64, 8), block 256 = 4 waves; 64n x 64m tile, K=512, kb step = head.
__global__ __launch_bounds__(256) void out_proj_kernel(
    const short* __restrict__ PO, const float* __restrict__ PL,
    const short* __restrict__ Wo, const float* __restrict__ bias,
    float* __restrict__ out)
{
    __shared__ short As[64 * 64];
    __shared__ short Bs[64 * 64];
    const int n0 = blockIdx.x * 64, m0 = blockIdx.y * 64;
    const int tid = threadIdx.x, w = tid >> 6, l = tid & 63;
    const int l15 = l & 15, lg = l >> 4;

    const f32x4 zero4 = {0.f, 0.f, 0.f, 0.f};
    f32x4 acc[4];
    #pragma unroll
    for (int dc = 0; dc < 4; ++dc) acc[dc] = zero4;

    for (int kb = 0; kb < 8; ++kb) {     // kb == head
        const int j0 = kb * 64;
        __syncthreads();
        #pragma unroll
        for (int i = 0; i < 2; ++i) {
            int c = tid + i * 256;
            int r = c >> 3, g = c & 7;
            int n = n0 + r;
            float le = 0.f;
            float se[8];
            #pragma unroll
            for (int e = 0; e < 8; ++e) se[e] = 0.f;
            #pragma unroll
            for (int pp = 0; pp < KSPLIT; ++pp) {
                size_t pbase = ((size_t)pp * NHEAD + kb) * N_TOK + n;
                le += PL[pbase];
                short8 ax = *(const short8*)(PO + pbase * 64 + g * 8);
                #pragma unroll
                for (int e = 0; e < 8; ++e) se[e] += bf2f(ax[e]);
            }
            float rl = 1.0f / le;
            short8 av;
            #pragma unroll
            for (int e = 0; e < 8; ++e) av[e] = f2bf(se[e] * rl);
            *(short8*)(As + r * 64 + ((g * 8) ^ ((r & 7) << 3))) = av;
            short8 bv = *(const short8*)(Wo + (size_t)(m0 + r) * 512 + j0 + g * 8);
            *(short8*)(Bs + r * 64 + ((g * 8) ^ ((r & 7) << 3))) = bv;
        }
        __syncthreads();
        const int arow = w * 16 + l15;
        short8 a0 = *(const short8*)(As + arow * 64 + ((lg * 8) ^ ((arow & 7) << 3)));
        short8 a1 = *(const short8*)(As + arow * 64 + ((32 + lg * 8) ^ ((arow & 7) << 3)));
        #pragma unroll
        for (int dc = 0; dc < 4; ++dc) {
            const int brow = dc * 16 + l15;
            short8 b0 = *(const short8*)(Bs + brow * 64 + ((lg * 8) ^ ((brow & 7) << 3)));
            acc[dc] = __builtin_amdgcn_mfma_f32_16x16x32_bf16(a0, b0, acc[dc], 0, 0, 0);
            short8 b1 = *(const short8*)(Bs + brow * 64 + ((32 + lg * 8) ^ ((brow & 7) << 3)));
            acc[dc] = __builtin_amdgcn_mfma_f32_16x16x32_bf16(a1, b1, acc[dc], 0, 0, 0);
        }
    }

    #pragma unroll
    for (int dc = 0; dc < 4; ++dc) {
        float bm = bias[m0 + dc * 16 + l15];
        #pragma unroll
        for (int reg = 0; reg < 4; ++reg) {
            int n = n0 + w * 16 + lg * 4 + reg;
            out[(size_t)n * D_MODEL + m0 + dc * 16 + l15] = acc[dc][reg] + bm;
        }
    }
}

extern "C" void kernel_launch(void* const* d_in, const int* in_sizes, int n_in,
                              void* d_out, int out_size, void* d_ws, size_t ws_size,
                              hipStream_t stream)
{
    const float* q      = (const float*)d_in[0];
    const float* k      = (const float*)d_in[1];
    const float* v      = (const float*)d_in[2];
    const float* coords = (const float*)d_in[3];
    const unsigned char* mask = (const unsigned char*)d_in[4];
    const float* q_proj = (const float*)d_in[5];
    const float* k_proj = (const float*)d_in[6];
    const float* v_proj = (const float*)d_in[7];
    const float* q_ln_w = (const float*)d_in[8];
    const float* q_ln_b = (const float*)d_in[9];
    const float* k_ln_w = (const float*)d_in[10];
    const float* k_ln_b = (const float*)d_in[11];
    const float* v_ln_w = (const float*)d_in[12];
    const float* v_ln_b = (const float*)d_in[13];
    const float* out_w  = (const float*)d_in[14];
    const float* out_b  = (const float*)d_in[15];
    float* out = (float*)d_out;

    // workspace layout (offsets in shorts), total ~27 MB (ws ~268 MB per fills)
    short* PO  = (short*)d_ws;             // 8*8*2048*64 bf16 = 16.8MB
    short* Wt  = PO + 8388608;             // 786,432
    short* Wo  = Wt + 786432;              // 262,144
    short* Qf  = Wo + 262144;              // 1,048,576 (fragment-ordered)
    short* Kf  = Qf + 1048576;             // 8 * KHEAD = 1,572,864 (main+aug)
    short* Vf  = Kf + 1572864;             // 1,048,576 (fragment-ordered)
    float* mpen = (float*)(Vf + 1048576);  // 2048 f32
    unsigned* tflag = (unsigned*)(mpen + 2048);  // 32 u32
    float* PL = (float*)(tflag + 32);      // 8*8*2048 f32

    prep_all_kernel<<<dim3(264), dim3(256), 0, stream>>>(
        coords, mask, q_proj, k_proj, v_proj, out_w, Wt, Wo, Kf, mpen, tflag);
    proj_ln_mfma_kernel<<<dim3(16, 8, 3), dim3(256), 0, stream>>>(
        q, k, v, Wt, q_ln_w, q_ln_b, k_ln_w, k_ln_b, v_ln_w, v_ln_b, Qf, Kf, Vf);
    attn_kernel<<<dim3(1024), dim3(256), 0, stream>>>(
        Qf, Kf, Vf, coords, mpen, tflag, PO, PL);
    out_proj_kernel<<<dim3(32, 8), dim3(256), 0, stream>>>(PO, PL, Wo, out_b, out);
}

// Round 18
// 66.770 us; speedup vs baseline: 1.6310x; 1.6310x over previous
//
#include <hip/hip_runtime.h>
#include <math.h>

#define N_TOK 2048
#define D_MODEL 512
#define NHEAD 8
#define DK 64
#define LOG2E 1.44269504f
#define QSCALE 0.18033688f   // 0.125 * log2(e)
#define KTILE 6144           // shorts per 64-key K tile (4096 main + 2048 aug)
#define KHEAD (32 * KTILE)   // shorts per head in Kf

typedef __attribute__((ext_vector_type(8))) short short8;
typedef __attribute__((ext_vector_type(4))) short short4v;
typedef __attribute__((ext_vector_type(4))) float f32x4;

__device__ __forceinline__ short f2bf(float x) {
    unsigned u = __float_as_uint(x);
    u = (u + 0x7fffu + ((u >> 16) & 1u)) >> 16;   // round-to-nearest-even
    return (short)u;
}

__device__ __forceinline__ float bf2f(short s) {
    return __uint_as_float(((unsigned)(unsigned short)s) << 16);
}

__device__ __forceinline__ void split2(float x, short& h_, short& l_) {
    h_ = f2bf(x);
    l_ = f2bf(x - bf2f(h_));
}

__device__ __forceinline__ void split3(float x, short& h_, short& m_, short& l_) {
    h_ = f2bf(x);
    float r = x - bf2f(h_);
    m_ = f2bf(r);
    l_ = f2bf(r - bf2f(m_));
}

__device__ __forceinline__ unsigned cvt_pk_bf16(float lo, float hi) {
    unsigned r;
    asm("v_cvt_pk_bf16_f32 %0, %1, %2" : "=v"(r) : "v"(lo), "v"(hi));
    return r;
}

__device__ __forceinline__ float head_c(int h) {
    // c_h = -log2e / (2*spread^2), spread = 1 + 5*(20^(h/7)-1)/19
    float tt = (float)h * (1.0f / 7.0f);
    float sp = 1.0f + 5.0f * (__builtin_exp2f(tt * 4.3219281f) - 1.0f) * (1.0f / 19.0f);
    return -LOG2E / (2.0f * sp * sp);
}

// ---------------- Prep (fused): x->bf16, weights->bf16, K-aug RBF frags ----
// bid <1536: convert q/k/v. 1536..1791: weight prep. 1792..1799: aug+mask.
__global__ __launch_bounds__(256) void prep_all_kernel(
    const float* __restrict__ q, const float* __restrict__ k,
    const float* __restrict__ v, const float* __restrict__ coords,
    const unsigned char* __restrict__ mask,
    const float* __restrict__ qp, const float* __restrict__ kp,
    const float* __restrict__ vp, const float* __restrict__ ow,
    short* __restrict__ Xbf, short* __restrict__ Wt, short* __restrict__ Wo,
    short* __restrict__ Kf, float* __restrict__ mpen,
    unsigned* __restrict__ tflag)
{
    __shared__ float tile[64][65];
    const int bid = blockIdx.x;
    const int t = threadIdx.x;

    if (bid < 1536) {
        // ---- convert x (q,k,v) f32 -> bf16 ----
        int i = bid * 256 + t;
        int tt = i >> 17;
        int rem = i & 131071;
        const float4* src = (const float4*)(tt == 0 ? q : (tt == 1 ? k : v));
        float4 a = src[rem * 2], b = src[rem * 2 + 1];
        short8 o;
        o[0] = f2bf(a.x); o[1] = f2bf(a.y); o[2] = f2bf(a.z); o[3] = f2bf(a.w);
        o[4] = f2bf(b.x); o[5] = f2bf(b.y); o[6] = f2bf(b.z); o[7] = f2bf(b.w);
        *(short8*)(Xbf + (size_t)i * 8) = o;
    } else if (bid < 1792) {
        // ---- weight prep ----
        int i = bid - 1536;                 // 0..255
        int z = i >> 6;                     // 0..3
        int bx = i & 7, by = (i >> 3) & 7;
        if (z == 3) {
            // Wo[m][h*64+kk] = out_w[m][kk*8+h]
            int m0 = bx * 64, j0 = by * 64, hh = by;
            for (int ii = t; ii < 4096; ii += 256) {
                int r = ii >> 6, kk = ii & 63;
                Wo[(size_t)(m0 + r) * 512 + j0 + kk] =
                    f2bf(ow[(size_t)(m0 + r) * 512 + kk * 8 + hh]);
            }
            return;
        }
        const float* src = z == 0 ? qp : (z == 1 ? kp : vp);
        const int h = bx, d0 = by * 64;
        for (int ii = t; ii < 4096; ii += 256) {
            int r = ii >> 6, c = ii & 63;
            tile[r][c] = src[((size_t)h * 512 + d0 + r) * 64 + c];
        }
        __syncthreads();
        short* W = Wt + (size_t)z * 512 * 512;
        for (int ii = t; ii < 4096; ii += 256) {
            int cr = ii >> 6, dc_ = ii & 63;
            W[(size_t)(h * 64 + cr) * 512 + d0 + dc_] = f2bf(tile[dc_][cr]);
        }
    } else {
        // ---- K-aug RBF fragments + mask tables ----
        int j = (bid - 1792) * 256 + t;
        float x = coords[j * 3 + 0], y = coords[j * 3 + 1], z = coords[j * 3 + 2];
        unsigned char mk = mask[j];
        mpen[j] = mk ? -1e9f : 0.f;
        unsigned long long b = __ballot(mk != 0);
        if ((t & 63) == 0) tflag[j >> 6] = (b != 0ull) ? 1u : 0u;
        float n2 = x * x + y * y + z * z;
        const short one = (short)0x3F80;
        const int kr = j & 15;
        #pragma unroll
        for (int h = 0; h < NHEAD; ++h) {
            float c = head_c(h);
            short ahx, alx, ahy, aly, ahz, alz, k2a, k2b, k2c;
            split2(-2.f * c * x, ahx, alx);
            split2(-2.f * c * y, ahy, aly);
            split2(-2.f * c * z, ahz, alz);
            split3(c * n2, k2a, k2b, k2c);
            // A-slot values kk=0..17 (rest zero):
            // [ahx,alx,ahx, ahy,aly,ahy, ahz,alz,ahz, alx,aly,alz, k2a,k2b,k2c, 1,1,1]
            short8 g0, g1, g2;
            g0[0] = ahx; g0[1] = alx; g0[2] = ahx; g0[3] = ahy;
            g0[4] = aly; g0[5] = ahy; g0[6] = ahz; g0[7] = alz;
            g1[0] = ahz; g1[1] = alx; g1[2] = aly; g1[3] = alz;
            g1[4] = k2a; g1[5] = k2b; g1[6] = k2c; g1[7] = one;
            g2[0] = one; g2[1] = one;
            #pragma unroll
            for (int e = 2; e < 8; ++e) g2[e] = 0;
            short8 g3;
            #pragma unroll
            for (int e = 0; e < 8; ++e) g3[e] = 0;
            // aug A-fragment chunk = 16 keys x 32 kk = 512 shorts; 4 chunks/tile
            short* base = Kf + (size_t)h * KHEAD + (size_t)(j >> 6) * KTILE
                        + 4096 + (size_t)((j >> 4) & 3) * 512;
            *(short8*)(base + (size_t)(0 * 16 + kr) * 8) = g0;   // kk 0..7
            *(short8*)(base + (size_t)(1 * 16 + kr) * 8) = g1;   // kk 8..15
            *(short8*)(base + (size_t)(2 * 16 + kr) * 8) = g2;   // kk 16..23
            *(short8*)(base + (size_t)(3 * 16 + kr) * 8) = g3;   // kk 24..31
        }
    }
}

// ---------------- Stage 1: projection + LayerNorm via bf16 MFMA ------------
// z=0: Q row-major [h][n][dk], pre-scaled by 0.125*log2e.
// z=1: K in MFMA-fragment tile order (KTILE stride; aug written by prep).
// z=2: V in fragment tile order (B=V^T A-op).
__global__ __launch_bounds__(256) void proj_ln_mfma_kernel(
    const short* __restrict__ Xbf, const short* __restrict__ Wt,
    const float* __restrict__ qlw, const float* __restrict__ qlb,
    const float* __restrict__ klw, const float* __restrict__ klb,
    const float* __restrict__ vlw, const float* __restrict__ vlb,
    short* __restrict__ Qbf, short* __restrict__ Kf, short* __restrict__ Vf)
{
    __shared__ short Xs[64 * 64];
    __shared__ short Ws[64 * 64];
    const int z = blockIdx.z, h = blockIdx.y;
    const int n0 = blockIdx.x * 64;
    const int tid = threadIdx.x, w = tid >> 6, l = tid & 63;
    const int l15 = l & 15, lg = l >> 4;

    const short* X = Xbf + (size_t)z * N_TOK * D_MODEL;
    const short* Wz = Wt + ((size_t)z * 512 + h * 64) * 512;

    const f32x4 zero4 = {0.f, 0.f, 0.f, 0.f};
    f32x4 acc[4];
    #pragma unroll
    for (int dc = 0; dc < 4; ++dc) acc[dc] = zero4;

    for (int kb = 0; kb < 8; ++kb) {
        const int d0 = kb * 64;
        __syncthreads();
        #pragma unroll
        for (int i = 0; i < 2; ++i) {
            int c = tid + i * 256;
            int r = c >> 3, g = c & 7;
            short8 xv = *(const short8*)(X + (size_t)(n0 + r) * 512 + d0 + g * 8);
            *(short8*)(Xs + r * 64 + ((g * 8) ^ ((r & 7) << 3))) = xv;
            short8 wv = *(const short8*)(Wz + (size_t)r * 512 + d0 + g * 8);
            *(short8*)(Ws + r * 64 + ((g * 8) ^ ((r & 7) << 3))) = wv;
        }
        __syncthreads();
        const int arow = w * 16 + l15;
        short8 a0 = *(const short8*)(Xs + arow * 64 + ((lg * 8) ^ ((arow & 7) << 3)));
        short8 a1 = *(const short8*)(Xs + arow * 64 + ((32 + lg * 8) ^ ((arow & 7) << 3)));
        #pragma unroll
        for (int dc = 0; dc < 4; ++dc) {
            const int brow = dc * 16 + l15;
            short8 b0 = *(const short8*)(Ws + brow * 64 + ((lg * 8) ^ ((brow & 7) << 3)));
            acc[dc] = __builtin_amdgcn_mfma_f32_16x16x32_bf16(a0, b0, acc[dc], 0, 0, 0);
            short8 b1 = *(const short8*)(Ws + brow * 64 + ((32 + lg * 8) ^ ((brow & 7) << 3)));
            acc[dc] = __builtin_amdgcn_mfma_f32_16x16x32_bf16(a1, b1, acc[dc], 0, 0, 0);
        }
    }

    const float* lw  = z == 0 ? qlw : (z == 1 ? klw : vlw);
    const float* lbp = z == 0 ? qlb : (z == 1 ? klb : vlb);
    float wv_[4], bv_[4];
    #pragma unroll
    for (int dc = 0; dc < 4; ++dc) {
        wv_[dc] = lw[dc * 16 + l15];
        bv_[dc] = lbp[dc * 16 + l15];
    }
    float mu[4], rs[4];
    #pragma unroll
    for (int reg = 0; reg < 4; ++reg) {
        float s = acc[0][reg] + acc[1][reg] + acc[2][reg] + acc[3][reg];
        #pragma unroll
        for (int off = 1; off < 16; off <<= 1) s += __shfl_xor(s, off);
        float m = s * (1.0f / 64.0f);
        float ss = 0.f;
        #pragma unroll
        for (int dc = 0; dc < 4; ++dc) { float d = acc[dc][reg] - m; ss += d * d; }
        #pragma unroll
        for (int off = 1; off < 16; off <<= 1) ss += __shfl_xor(ss, off);
        mu[reg] = m;
        rs[reg] = rsqrtf(ss * (1.0f / 64.0f) + 1e-5f);
    }

    const int tile = n0 >> 6;
    if (z == 0) {
        #pragma unroll
        for (int dc = 0; dc < 4; ++dc)
            #pragma unroll
            for (int reg = 0; reg < 4; ++reg) {
                int n = n0 + w * 16 + lg * 4 + reg;
                float val = ((acc[dc][reg] - mu[reg]) * rs[reg] * wv_[dc] + bv_[dc]) * QSCALE;
                Qbf[((size_t)h * N_TOK + n) * DK + dc * 16 + l15] = f2bf(val);
            }
    } else if (z == 1) {
        // main chunks: Kf[h] + tile*KTILE + (nc*2+hf)*512 + ...
        short* Kh = Kf + (size_t)h * KHEAD;
        #pragma unroll
        for (int dc = 0; dc < 4; ++dc) {
            int hf  = dc >> 1;
            int lgc = ((dc & 1) << 1) | (l15 >> 3);
            int e   = l15 & 7;
            size_t base = (size_t)tile * KTILE + (w * 2 + hf) * 512 + 16 * 8 * lgc + e;
            #pragma unroll
            for (int reg = 0; reg < 4; ++reg) {
                float val = (acc[dc][reg] - mu[reg]) * rs[reg] * wv_[dc] + bv_[dc];
                Kh[base + (lg * 4 + reg) * 8] = f2bf(val);
            }
        }
    } else {
        // fragment order: Vf[h] + tile*4096 + (dcc*2+hf)*512 + (l15+16*lgv)*8 + e
        short* Vh = Vf + (size_t)h * N_TOK * DK;
        int hfv = w >> 1;
        int lgv = ((w & 1) << 1) | (lg >> 1);
        int eb  = (lg & 1) * 4;
        #pragma unroll
        for (int dc = 0; dc < 4; ++dc) {
            short4v p;
            #pragma unroll
            for (int reg = 0; reg < 4; ++reg)
                p[reg] = f2bf((acc[dc][reg] - mu[reg]) * rs[reg] * wv_[dc] + bv_[dc]);
            size_t addr = (size_t)tile * 4096 + (dc * 2 + hfv) * 512 + (l15 + 16 * lgv) * 8 + eb;
            *(short4v*)(Vh + addr) = p;
        }
    }
}

// ---------------- Stage 2: split-K flash attention (bf16 MFMA) -------------
// 1-D grid 2048, head<->XCD affinity (h = bid&7). Block covers keys
// [z*1024,(z+1)*1024); wave w covers 256 keys in 4 steps of 64.
// RBF arg computed via a second MFMA per nc against precomputed augmented
// K fragments (hi/lo compensated bf16 splits; Δarg < ~0.002 log2):
// no per-pair table loads or fma chains. m=0 softmax; l via ones-MFMA.
__global__ __launch_bounds__(256) void attn_kernel(
    const short* __restrict__ Qbf, const short* __restrict__ Kf,
    const short* __restrict__ Vf, const float* __restrict__ coords,
    const float* __restrict__ mpen, const unsigned* __restrict__ tflag,
    short* __restrict__ PO, float* __restrict__ PL)
{
    __shared__ short Pls[4][1024];       // per-wave P [16 q][64 k], swizzled
    __shared__ float bufO[2][64][17];
    __shared__ float bufL[2][64];

    const int tid = threadIdx.x;
    const int w = tid >> 6, l = tid & 63;
    const int l15 = l & 15, lg = l >> 4;
    const int bid = blockIdx.x;
    const int h  = bid & 7;              // head == XCD
    const int nt = (bid >> 3) & 127;
    const int z  = bid >> 10;
    const int n0 = nt * 16;

    char* Pb = (char*)&Pls[w][0];
    const int psw = (l15 & 7) << 4;      // byte-xor swizzle within 128B row

    // Q B-fragments (row q = n0+l15, d-halves)
    const short* Qrow = Qbf + ((size_t)h * N_TOK + n0 + l15) * DK + lg * 8;
    const short8 qf0 = *(const short8*)(Qrow);
    const short8 qf1 = *(const short8*)(Qrow + 32);

    // Q-side augmented RBF fragment (B[kk][q], kk = lg*8+e)
    const float ch = head_c(h);
    const float qx = coords[(n0 + l15) * 3 + 0];
    const float qy = coords[(n0 + l15) * 3 + 1];
    const float qz = coords[(n0 + l15) * 3 + 2];
    const float cq2 = ch * (qx * qx + qy * qy + qz * qz);
    short8 qaug;
    {
        const short one = (short)0x3F80;
        short qhx, qlx, qhy, qly, qhz, qlz, q2a, q2b, q2c;
        split2(qx, qhx, qlx);
        split2(qy, qhy, qly);
        split2(qz, qhz, qlz);
        split3(cq2, q2a, q2b, q2c);
        #pragma unroll
        for (int e = 0; e < 8; ++e) qaug[e] = 0;
        if (lg == 0) {
            qaug[0] = qhx; qaug[1] = qhx; qaug[2] = qlx; qaug[3] = qhy;
            qaug[4] = qhy; qaug[5] = qly; qaug[6] = qhz; qaug[7] = qhz;
        } else if (lg == 1) {
            qaug[0] = qlz; qaug[1] = qlx; qaug[2] = qly; qaug[3] = qlz;
            qaug[4] = one; qaug[5] = one; qaug[6] = one; qaug[7] = q2a;
        } else if (lg == 2) {
            qaug[0] = q2b; qaug[1] = q2c;
        }
    }

    // all-ones bf16 A-fragment for the l row-sum MFMA
    short8 ones8;
    #pragma unroll
    for (int i = 0; i < 8; ++i) ones8[i] = (short)0x3F80;

    const f32x4 zero4 = {0.f, 0.f, 0.f, 0.f};
    f32x4 oacc[4];
    f32x4 oacc_l = zero4;
    #pragma unroll
    for (int i = 0; i < 4; ++i) oacc[i] = zero4;

    const short* Kfh = Kf + (size_t)h * KHEAD;
    const short* Vfh = Vf + (size_t)h * N_TOK * DK;

    for (int t = 0; t < 4; ++t) {
        const int kt = (z * 4 + w) * 4 + t;  // global 64-key tile
        const int kbase = kt * 64;
        const short* kp = Kfh + (size_t)kt * KTILE + l * 8;
        const short* ap = kp + 4096;
        const short* vp = Vfh + (size_t)kt * 4096 + l * 8;

        // ---- QK^T (swapped) + RBF-arg MFMA: lane q=l15, k=nc*16+lg*4+reg ----
        f32x4 sacc[4], aacc[4];
        #pragma unroll
        for (int nc = 0; nc < 4; ++nc) {
            short8 k0 = *(const short8*)(kp + nc * 1024);
            short8 k1 = *(const short8*)(kp + nc * 1024 + 512);
            short8 ka = *(const short8*)(ap + nc * 512);
            sacc[nc] = __builtin_amdgcn_mfma_f32_16x16x32_bf16(k0, qf0, zero4, 0, 0, 0);
            sacc[nc] = __builtin_amdgcn_mfma_f32_16x16x32_bf16(k1, qf1, sacc[nc], 0, 0, 0);
            aacc[nc] = __builtin_amdgcn_mfma_f32_16x16x32_bf16(ka, qaug, zero4, 0, 0, 0);
        }

        // ---- RBF modulation: rb = clamp(exp2(arg)); s *= rb ----
        #pragma unroll
        for (int nc = 0; nc < 4; ++nc) {
            #pragma unroll
            for (int reg = 0; reg < 4; ++reg) {
                float rb = __builtin_exp2f(aacc[nc][reg]);
                rb = fminf(fmaxf(rb, 0.1f), 0.9f);
                sacc[nc][reg] *= rb;
            }
        }
        if (tflag[kt]) {
            #pragma unroll
            for (int nc = 0; nc < 4; ++nc)
                #pragma unroll
                for (int reg = 0; reg < 4; ++reg)
                    sacc[nc][reg] += mpen[kbase + nc * 16 + lg * 4 + reg];
        }

        // ---- P = exp2(s) (m=0), pack -> LDS ----
        #pragma unroll
        for (int nc = 0; nc < 4; ++nc) {
            float p0 = __builtin_exp2f(sacc[nc][0]);
            float p1 = __builtin_exp2f(sacc[nc][1]);
            float p2 = __builtin_exp2f(sacc[nc][2]);
            float p3 = __builtin_exp2f(sacc[nc][3]);
            uint2 u;
            u.x = cvt_pk_bf16(p0, p1);
            u.y = cvt_pk_bf16(p2, p3);
            *(uint2*)(Pb + ((l15 * 128 + nc * 32 + lg * 8) ^ psw)) = u;
        }

        // ---- PV (swapped): O^T += V^T * P^T; l += 1 * P^T (ones-MFMA) ----
        short8 pf0 = *(const short8*)(Pb + ((l15 * 128 + lg * 16) ^ psw));
        short8 pf1 = *(const short8*)(Pb + ((l15 * 128 + 64 + lg * 16) ^ psw));
        #pragma unroll
        for (int dcc = 0; dcc < 4; ++dcc) {
            short8 v0 = *(const short8*)(vp + dcc * 1024);
            short8 v1 = *(const short8*)(vp + dcc * 1024 + 512);
            oacc[dcc] = __builtin_amdgcn_mfma_f32_16x16x32_bf16(v0, pf0, oacc[dcc], 0, 0, 0);
            oacc[dcc] = __builtin_amdgcn_mfma_f32_16x16x32_bf16(v1, pf1, oacc[dcc], 0, 0, 0);
        }
        oacc_l = __builtin_amdgcn_mfma_f32_16x16x32_bf16(ones8, pf0, oacc_l, 0, 0, 0);
        oacc_l = __builtin_amdgcn_mfma_f32_16x16x32_bf16(ones8, pf1, oacc_l, 0, 0, 0);
    }

    float l_ = oacc_l[0];   // every reg holds l[q=l15]

    // ---- cross-wave tree merge (m=0: plain sums, lane-aligned) ----
    if (w >= 2) {
        int slot = w - 2;
        bufL[slot][l] = l_;
        #pragma unroll
        for (int dc = 0; dc < 4; ++dc)
            #pragma unroll
            for (int reg = 0; reg < 4; ++reg)
                bufO[slot][l][dc * 4 + reg] = oacc[dc][reg];
    }
    __syncthreads();
    if (w < 2) {
        l_ += bufL[w][l];
        #pragma unroll
        for (int dc = 0; dc < 4; ++dc)
            #pragma unroll
            for (int reg = 0; reg < 4; ++reg)
                oacc[dc][reg] += bufO[w][l][dc * 4 + reg];
    }
    __syncthreads();
    if (w == 1) {
        bufL[0][l] = l_;
        #pragma unroll
        for (int dc = 0; dc < 4; ++dc)
            #pragma unroll
            for (int reg = 0; reg < 4; ++reg)
                bufO[0][l][dc * 4 + reg] = oacc[dc][reg];
    }
    __syncthreads();
    if (w == 0) {
        float lf = l_ + bufL[0][l];
        size_t p = ((size_t)z * NHEAD + h) * N_TOK + n0 + l15;
        if (lg == 0) PL[p] = lf;
        #pragma unroll
        for (int dcc = 0; dcc < 4; ++dcc) {
            short4v o4;
            #pragma unroll
            for (int reg = 0; reg < 4; ++reg)
                o4[reg] = f2bf(oacc[dcc][reg] + bufO[0][l][dcc * 4 + reg]);
            *(short4v*)(PO + p * 64 + dcc * 16 + lg * 4) = o4;
        }
    }
}

// ---------------- Stage 3: merge partials + output projection (fused) ------
// grid (N/64, 8), block 256 = 4 waves; 64n x 64m tile, K=512, kb step = head.
// A-tile staging merges the 2 KV-split partials (PO,PL) and normalizes.
__global__ __launch_bounds__(256) void out_proj_kernel(
    const short* __restrict__ PO, const float* __restrict__ PL,
    const short* __restrict__ Wo, const float* __restrict__ bias,
    float* __restrict__ out)
{
    __shared__ short As[64 * 64];
    __shared__ short Bs[64 * 64];
    const int n0 = blockIdx.x * 64, m0 = blockIdx.y * 64;
    const int tid = threadIdx.x, w = tid >> 6, l = tid & 63;
    const int l15 = l & 15, lg = l >> 4;

    const f32x4 zero4 = {0.f, 0.f, 0.f, 0.f};
    f32x4 acc[4];
    #pragma unroll
    for (int dc = 0; dc < 4; ++dc) acc[dc] = zero4;

    for (int kb = 0; kb < 8; ++kb) {     // kb == head
        const int j0 = kb * 64;
        __syncthreads();
        #pragma unroll
        for (int i = 0; i < 2; ++i) {
            int c = tid + i * 256;
            int r = c >> 3, g = c & 7;
            int n = n0 + r;
            size_t p0 = (size_t)kb * N_TOK + n;
            size_t p1 = (size_t)(NHEAD + kb) * N_TOK + n;
            float rl = 1.0f / (PL[p0] + PL[p1]);
            short8 a0 = *(const short8*)(PO + p0 * 64 + g * 8);
            short8 a1 = *(const short8*)(PO + p1 * 64 + g * 8);
            short8 av;
            #pragma unroll
            for (int e = 0; e < 8; ++e)
                av[e] = f2bf((bf2f(a0[e]) + bf2f(a1[e])) * rl);
            *(short8*)(As + r * 64 + ((g * 8) ^ ((r & 7) << 3))) = av;
            short8 bv = *(const short8*)(Wo + (size_t)(m0 + r) * 512 + j0 + g * 8);
            *(short8*)(Bs + r * 64 + ((g * 8) ^ ((r & 7) << 3))) = bv;
        }
        __syncthreads();
        const int arow = w * 16 + l15;
        short8 a0 = *(const short8*)(As + arow * 64 + ((lg * 8) ^ ((arow & 7) << 3)));
        short8 a1 = *(const short8*)(As + arow * 64 + ((32 + lg * 8) ^ ((arow & 7) << 3)));
        #pragma unroll
        for (int dc = 0; dc < 4; ++dc) {
            const int brow = dc * 16 + l15;
            short8 b0 = *(const short8*)(Bs + brow * 64 + ((lg * 8) ^ ((brow & 7) << 3)));
            acc[dc] = __builtin_amdgcn_mfma_f32_16x16x32_bf16(a0, b0, acc[dc], 0, 0, 0);
            short8 b1 = *(const short8*)(Bs + brow * 64 + ((32 + lg * 8) ^ ((brow & 7) << 3)));
            acc[dc] = __builtin_amdgcn_mfma_f32_16x16x32_bf16(a1, b1, acc[dc], 0, 0, 0);
        }
    }

    #pragma unroll
    for (int dc = 0; dc < 4; ++dc) {
        float bm = bias[m0 + dc * 16 + l15];
        #pragma unroll
        for (int reg = 0; reg < 4; ++reg) {
            int n = n0 + w * 16 + lg * 4 + reg;
            out[(size_t)n * D_MODEL + m0 + dc * 16 + l15] = acc[dc][reg] + bm;
        }
    }
}

extern "C" void kernel_launch(void* const* d_in, const int* in_sizes, int n_in,
                              void* d_out, int out_size, void* d_ws, size_t ws_size,
                              hipStream_t stream)
{
    const float* q      = (const float*)d_in[0];
    const float* k      = (const float*)d_in[1];
    const float* v      = (const float*)d_in[2];
    const float* coords = (const float*)d_in[3];
    const unsigned char* mask = (const unsigned char*)d_in[4];
    const float* q_proj = (const float*)d_in[5];
    const float* k_proj = (const float*)d_in[6];
    const float* v_proj = (const float*)d_in[7];
    const float* q_ln_w = (const float*)d_in[8];
    const float* q_ln_b = (const float*)d_in[9];
    const float* k_ln_w = (const float*)d_in[10];
    const float* k_ln_b = (const float*)d_in[11];
    const float* v_ln_w = (const float*)d_in[12];
    const float* v_ln_b = (const float*)d_in[13];
    const float* out_w  = (const float*)d_in[14];
    const float* out_b  = (const float*)d_in[15];
    float* out = (float*)d_out;

    // workspace layout (offsets in shorts), total ~15.7 MB
    short* Xbf = (short*)d_ws;             // 3,145,728
    short* Wt  = Xbf + 3145728;            // 786,432
    short* Wo  = Wt + 786432;              // 262,144
    short* Qbf = Wo + 262144;              // 1,048,576
    short* Kf  = Qbf + 1048576;            // 8 * KHEAD = 1,572,864 (main+aug)
    short* Vf  = Kf + 1572864;             // 1,048,576
    float* mpen = (float*)(Vf + 1048576);  // 2048 f32
    unsigned* tflag = (unsigned*)(mpen + 2048);  // 32 u32

    // overlays: Xbf/Wt are dead once proj_ln_mfma has run (stream-ordered)
    short* PO = Xbf;                       // 2*8*2048*64 bf16 = 4.2MB
    float* PL = (float*)Wt;                // 2*8*2048 f32

    prep_all_kernel<<<dim3(1800), dim3(256), 0, stream>>>(
        q, k, v, coords, mask, q_proj, k_proj, v_proj, out_w,
        Xbf, Wt, Wo, Kf, mpen, tflag);
    proj_ln_mfma_kernel<<<dim3(32, 8, 3), dim3(256), 0, stream>>>(
        Xbf, Wt, q_ln_w, q_ln_b, k_ln_w, k_ln_b, v_ln_w, v_ln_b, Qbf, Kf, Vf);
    attn_kernel<<<dim3(2048), dim3(256), 0, stream>>>(
        Qbf, Kf, Vf, coords, mpen, tflag, PO, PL);
    out_proj_kernel<<<dim3(32, 8), dim3(256), 0, stream>>>(PO, PL, Wo, out_b, out);
}